// Round 9
// baseline (194.703 us; speedup 1.0000x reference)
//
#include <hip/hip_runtime.h>

#define HEADS 16
#define NQ    2048
#define NKV   4096
#define DH    128
#define PDIM  64

typedef __bf16 bf16_t;
typedef bf16_t bf16x8 __attribute__((ext_vector_type(8)));
typedef bf16_t bf16x4 __attribute__((ext_vector_type(4)));
typedef bf16_t bf16x2 __attribute__((ext_vector_type(2)));
typedef float  f32x4  __attribute__((ext_vector_type(4)));
typedef float  f32x16 __attribute__((ext_vector_type(16)));
typedef int    i32x4  __attribute__((ext_vector_type(4)));

// ---------------------------------------------------------------------------
// prep (r6-proven: merged 3-launch pipeline):
//   blocks [0,512):      Q -> Qp (scaled by (1/8)*log2e)   [proj path]
//   blocks [512,1536):   K -> Kp                            [proj path]
//   blocks [1536,2560):  V -> Vt (bf16 transpose)           [vtrans path]
// ---------------------------------------------------------------------------
__global__ __launch_bounds__(256) void prep_kernel(
    const float* __restrict__ Q, const float* __restrict__ K,
    const float* __restrict__ V, const float* __restrict__ R,
    bf16_t* __restrict__ Qp, bf16_t* __restrict__ Kp, bf16_t* __restrict__ Vt)
{
  __shared__ char lds[32768];
  const int tid = threadIdx.x;
  const int bid = blockIdx.x;

  if (bid >= 1536) {
    // ---- V transpose path ----
    float* sF = (float*)lds;                   // 64 x 128 f32, granule-swizzled
    const int vb = bid - 1536;
    const float* tp = V + (long)vb * 64 * DH;
#pragma unroll
    for (int rep = 0; rep < 8; ++rep) {
      const int slot = tid + rep * 256;        // 2048 granules: 64 rows x 32
      const int j = slot >> 5, g = slot & 31;
      f32x4 v = *(const f32x4*)(tp + j * DH + g * 4);
      *(f32x4*)(&sF[j * 128 + ((g ^ ((j >> 3) & 7)) << 2)]) = v;
    }
    __syncthreads();

    const int h = vb >> 6, jt = vb & 63;
    bf16_t* op = Vt + (long)h * DH * NKV + jt * 64;
#pragma unroll
    for (int rep = 0; rep < 4; ++rep) {
      const int slot = tid + rep * 256;        // 1024 slots: 128 d x 8 j-groups
      const int d = slot >> 3, j8 = (slot & 7) * 8;
      const int key = slot & 7;                // == (j>>3)&7 for j in [j8,j8+8)
      const int gsw = (((d >> 2) ^ key) << 2) + (d & 3);
      bf16x8 w;
#pragma unroll
      for (int jj = 0; jj < 8; ++jj) w[jj] = (bf16_t)sF[(j8 + jj) * 128 + gsw];
      *(bf16x8*)(op + (long)d * NKV + j8) = w;
    }
    return;
  }

  // ---- projection path (Q or K) ----
  bf16_t* sR = (bf16_t*)lds;                   // [64][136] bf16 (17.4 KB)
  bf16_t* sYb = (bf16_t*)(lds + 64 * 136 * 2); // 4 x [16*72] bf16 (9.2 KB)

  const int isQ = (bid < 512);
  const float* src = isQ ? Q : K;
  const long row0  = isQ ? (long)bid * 64 : (long)(bid - 512) * 64;
  const float scale = isQ ? 0.18033688011112042f : 1.0f;   // (1/8)*log2(e)
  bf16_t* Y = isQ ? Qp : Kp;

  // R -> LDS transpose: sR[n][k] = R[k][n]; reads R linearly (coalesced).
#pragma unroll
  for (int rep = 0; rep < 32; ++rep) {
    const int idx = tid + rep * 256;           // 8192 elems, k = idx>>6, n low
    sR[(idx & 63) * 136 + (idx >> 6)] = (bf16_t)R[idx];
  }
  __syncthreads();

  const int wave = tid >> 6, lane = tid & 63;
  const int n16  = lane & 15, quad = lane >> 4;

  // B fragments: B[k][n], n = nt*16+n16, k = kk*32 + quad*8 + j
  bf16x8 bfr[4][4];
#pragma unroll
  for (int nt = 0; nt < 4; ++nt)
#pragma unroll
    for (int kk = 0; kk < 4; ++kk)
      bfr[nt][kk] = *(const bf16x8*)(sR + (nt * 16 + n16) * 136 + kk * 32 + quad * 8);

  // A fragments: row = wave*16 + n16, k = kk*32 + quad*8 + j, direct global
  const int arow = wave * 16 + n16;
  const float* xp = src + (row0 + arow) * DH;
  bf16x8 a[4];
#pragma unroll
  for (int kk = 0; kk < 4; ++kk) {
    const int k0 = kk * 32 + quad * 8;
    f32x4 x0 = *(const f32x4*)(xp + k0);
    f32x4 x1 = *(const f32x4*)(xp + k0 + 4);
    bf16x8 av;
#pragma unroll
    for (int j = 0; j < 4; ++j) { av[j] = (bf16_t)(x0[j] * scale); av[4 + j] = (bf16_t)(x1[j] * scale); }
    a[kk] = av;
  }

  bf16_t* sy = sYb + wave * (16 * 72);
#pragma unroll
  for (int nt = 0; nt < 4; ++nt) {
    f32x4 acc = {0.f, 0.f, 0.f, 0.f};
#pragma unroll
    for (int kk = 0; kk < 4; ++kk)
      acc = __builtin_amdgcn_mfma_f32_16x16x32_bf16(a[kk], bfr[nt][kk], acc, 0, 0, 0);
#pragma unroll
    for (int r = 0; r < 4; ++r)
      sy[(quad * 4 + r) * 72 + nt * 16 + n16] = (bf16_t)acc[r];
  }
  // coalesced store: lane -> (row = lane>>2, colgroup = lane&3)
  const long xrow = row0 + wave * 16;
  const int row = lane >> 2, cg = lane & 3;
  bf16x8 w0 = *(const bf16x8*)(&sy[row * 72 + cg * 16]);
  bf16x8 w1 = *(const bf16x8*)(&sy[row * 72 + cg * 16 + 8]);
  *(bf16x8*)(Y + (xrow + row) * PDIM + cg * 16)     = w0;
  *(bf16x8*)(Y + (xrow + row) * PDIM + cg * 16 + 8) = w1;
}

// ---------------------------------------------------------------------------
// flash v11 = v9 structure (4 waves x 32 q, 64 acc regs, occ ~34%) + T14
// reg-staged async pipeline replacing global_load_lds:
//   * issue 6 x dwordx4 global loads for tile t+1 BEFORE computing tile t
//     (in-flight REG loads can't alias LDS -> no forced vmcnt before the
//     ds_reads, unlike r1's global_load_lds prefetch trap);
//   * post-compute __syncthreads' vmcnt(0) lands after ~5K cyc of compute
//     has hidden the latency -> drain nearly free;
//   * 6 x ds_write_b128 with the XOR chunk swizzle applied at the LDS dest
//     (read side unchanged); global reads now strictly linear.
// Per r8's accounting the common ~40% stall across v4/v9/v10 is the
// dma16 -> vmcnt(0) -> barrier serial drain; this removes it.
// Tripwires: FETCH ~14 MB / WRITE ~33 MB, VGPR <= ~128; else revert v9.
// ---------------------------------------------------------------------------
__global__ __launch_bounds__(256, 3) void flash_kernel(
    const bf16_t* __restrict__ Qp, const bf16_t* __restrict__ Kp,
    const bf16_t* __restrict__ Vt, bf16_t* __restrict__ Opart,
    float* __restrict__ Lpart, float* __restrict__ Out,
    int splits, int iters)
{
  __shared__ char smem[34816];           // staging 24 KB; epilogue 34.8 KB
  bf16_t* sK = (bf16_t*)smem;            // 64 rows x 64, swizzled chunks (8 KB)
  bf16_t* sV = (bf16_t*)(smem + 8192);   // 128 rows x 64, swizzled (16 KB)
  bf16_t* sB = (bf16_t*)smem;            // staging write base (elems)

  const int tid  = threadIdx.x;
  const int wave = tid >> 6, lane = tid & 63;
  const int l31  = lane & 31, h = lane >> 5;

  const int head = blockIdx.x & 15;      // XCD round-robin -> 2 heads/XCD
  const int qt   = (blockIdx.x >> 4) & 15;
  const int sp   = blockIdx.x >> 8;

  const int qbase = qt * 128 + wave * 32;   // each wave owns 32 q rows
  const int kv0   = sp * (64 * iters);

  // persistent Q B-frags: B[k=p][n=q], q = l31, p = k*16 + 8h + j
  bf16x8 qf[4];
#pragma unroll
  for (int k = 0; k < 4; ++k)
    qf[k] = *(const bf16x8*)(Qp + ((long)head * NQ + qbase + l31) * PDIM
                             + k * 16 + h * 8);

  f32x16 o[4] = {};             // O^T accum: [dsub], C layout (64 regs)
  float rsum = 0.f;             // per-lane partial row sum

  const bf16_t* kpH = Kp + (long)head * NKV * PDIM;
  const bf16_t* vtH = Vt + (long)head * DH * NKV;

  // ---- T14 staging geometry (tid-constant) ----
  // 24 KB/tile = 1536 x 16B chunks; 6 per thread:
  //   i=0,1: K rows krow, krow+32 (64 rows x 8 chunks)
  //   i=2..5: V rows krow+{0,32,64,96} (128 rows x 8 chunks)
  // LDS elem offset: row*64 + ((c16 ^ (row&7))*8); (row+32)&7 == row&7, so
  // all six destinations = base + {0,2048,4096,6144,8192,10240}.
  const int krow = tid >> 3, kc16 = tid & 7;
  const int lof0 = krow * 64 + ((kc16 ^ (krow & 7)) * 8);
  i32x4 g0, g1, g2, g3, g4, g5;

#define LOAD_STAGE(KVB)                                                       \
  {                                                                           \
    const int kb_ = (KVB);                                                    \
    g0 = *(const i32x4*)(kpH + (long)(kb_ + krow) * PDIM + kc16 * 8);         \
    g1 = *(const i32x4*)(kpH + (long)(kb_ + krow + 32) * PDIM + kc16 * 8);    \
    g2 = *(const i32x4*)(vtH + (long)(krow) * NKV + kb_ + kc16 * 8);          \
    g3 = *(const i32x4*)(vtH + (long)(krow + 32) * NKV + kb_ + kc16 * 8);     \
    g4 = *(const i32x4*)(vtH + (long)(krow + 64) * NKV + kb_ + kc16 * 8);     \
    g5 = *(const i32x4*)(vtH + (long)(krow + 96) * NKV + kb_ + kc16 * 8);     \
  }
#define WRITE_STAGE()                                                         \
  {                                                                           \
    *(i32x4*)(sB + lof0)         = g0;                                        \
    *(i32x4*)(sB + lof0 + 2048)  = g1;                                        \
    *(i32x4*)(sB + lof0 + 4096)  = g2;                                        \
    *(i32x4*)(sB + lof0 + 6144)  = g3;                                        \
    *(i32x4*)(sB + lof0 + 8192)  = g4;                                        \
    *(i32x4*)(sB + lof0 + 10240) = g5;                                        \
  }

  // prologue: stage tile 0
  LOAD_STAGE(kv0);
  WRITE_STAGE();
  __syncthreads();

  for (int t = 0; t < iters; ++t) {
    // issue-early: next tile's global loads go out before this tile's compute
    if (t + 1 < iters) LOAD_STAGE(kv0 + (t + 1) * 64);

#pragma unroll
    for (int s = 0; s < 2; ++s) {
      // QK: S^T tile [32 kv][32 q], kv row = s*32 + l31
      f32x16 sc = {};
      const int r = s * 32 + l31;
#pragma unroll
      for (int k = 0; k < 4; ++k) {
        const int c = 2 * k + h;
        const bf16x8 a = *(const bf16x8*)(sK + r * 64 + ((c ^ (r & 7)) * 8));
        sc = __builtin_amdgcn_mfma_f32_32x32x16_bf16(a, qf[k], sc, 0, 0, 0);
      }
      // exp2 (log2-domain, fixed max 0) + pack + per-lane rsum
      int pk[4][2];
#pragma unroll
      for (int rg = 0; rg < 4; ++rg) {
        const float p0 = __builtin_amdgcn_exp2f(sc[rg * 4 + 0]);
        const float p1 = __builtin_amdgcn_exp2f(sc[rg * 4 + 1]);
        const float p2 = __builtin_amdgcn_exp2f(sc[rg * 4 + 2]);
        const float p3 = __builtin_amdgcn_exp2f(sc[rg * 4 + 3]);
        rsum += (p0 + p1) + (p2 + p3);
        union { bf16x2 v; int i; } u0, u1;
        u0.v = bf16x2{(bf16_t)p0, (bf16_t)p1};
        u1.v = bf16x2{(bf16_t)p2, (bf16_t)p3};
        pk[rg][0] = u0.i; pk[rg][1] = u1.i;
      }
      // C-layout -> B-layout: j0-3 = half0's pk[2cl+h], j4-7 = half1's
      int bfr[2][4];
#pragma unroll
      for (int cl = 0; cl < 2; ++cl) {
        const int e00 = __shfl_xor(pk[2 * cl][0], 32);
        const int e01 = __shfl_xor(pk[2 * cl][1], 32);
        const int e10 = __shfl_xor(pk[2 * cl + 1][0], 32);
        const int e11 = __shfl_xor(pk[2 * cl + 1][1], 32);
        bfr[cl][0] = h ? e10 : pk[2 * cl][0];
        bfr[cl][1] = h ? e11 : pk[2 * cl][1];
        bfr[cl][2] = h ? pk[2 * cl + 1][0] : e00;
        bfr[cl][3] = h ? pk[2 * cl + 1][1] : e01;
      }
      // PV for this s: kv steps c = 2s + cl
#pragma unroll
      for (int dsub = 0; dsub < 4; ++dsub) {
        const int rr = dsub * 32 + l31;
#pragma unroll
        for (int cl = 0; cl < 2; ++cl) {
          const int c = 2 * (2 * s + cl) + h;
          const bf16x8 va = *(const bf16x8*)(sV + rr * 64 + ((c ^ (rr & 7)) * 8));
          union { i32x4 i; bf16x8 v; } pb;
          pb.i = i32x4{bfr[cl][0], bfr[cl][1], bfr[cl][2], bfr[cl][3]};
          o[dsub] = __builtin_amdgcn_mfma_f32_32x32x16_bf16(va, pb.v, o[dsub], 0, 0, 0);
        }
      }
    }

    __syncthreads();                       // all waves done reading tile t
    if (t + 1 < iters) WRITE_STAGE();      // regs (long in flight) -> LDS
    __syncthreads();                       // tile t+1 visible
  }

  // epilogue: transpose O^T -> row-major via wave-private LDS, store coalesced
  __syncthreads();
  bf16_t* myT = (bf16_t*)(smem + wave * 8704);   // 32 rows x 272 B (136 elems)
  const float lsum = rsum + __shfl_xor(rsum, 32);
  const float scale = (splits > 1) ? 1.0f : (1.0f / lsum);
#pragma unroll
  for (int dsub = 0; dsub < 4; ++dsub)
#pragma unroll
    for (int rg = 0; rg < 4; ++rg) {
      bf16x4 w = { (bf16_t)(o[dsub][rg * 4 + 0] * scale),
                   (bf16_t)(o[dsub][rg * 4 + 1] * scale),
                   (bf16_t)(o[dsub][rg * 4 + 2] * scale),
                   (bf16_t)(o[dsub][rg * 4 + 3] * scale) };
      *(bf16x4*)(myT + l31 * 136 + dsub * 32 + rg * 8 + h * 4) = w;
    }
#pragma unroll
  for (int j = 0; j < 8; ++j) {
    const int ql = j * 4 + (lane >> 4);
    bf16x8 v = *(const bf16x8*)(myT + ql * 136 + (lane & 15) * 8);
    if (splits > 1) {
      *(bf16x8*)(Opart + (((long)sp * HEADS + head) * NQ + qbase + ql) * DH + (lane & 15) * 8) = v;
    } else {
      float* op = Out + ((long)head * NQ + qbase + ql) * DH + (lane & 15) * 8;
      f32x4 a = {(float)v[0], (float)v[1], (float)v[2], (float)v[3]};
      f32x4 b = {(float)v[4], (float)v[5], (float)v[6], (float)v[7]};
      *(f32x4*)op = a; *(f32x4*)(op + 4) = b;
    }
  }
  if (splits > 1 && h == 0)
    Lpart[((long)sp * HEADS + head) * NQ + qbase + l31] = lsum;
}

// ---------------------------------------------------------------------------
// combine: Out[hq][d] = (sum_s Opart[s][hq][d]) / (sum_s Lpart[s][hq])
// (round-0 form, fixed 4 splits)
// ---------------------------------------------------------------------------
__global__ __launch_bounds__(256) void combine_kernel(
    const bf16_t* __restrict__ Opart, const float* __restrict__ Lpart,
    float* __restrict__ Out)
{
  const long idx = (long)blockIdx.x * 256 + threadIdx.x;
  const int  d8  = (int)(idx & 15);
  const long hq  = idx >> 4;
  float l = 0.f;
  float acc[8];
#pragma unroll
  for (int j = 0; j < 8; ++j) acc[j] = 0.f;
#pragma unroll
  for (int s = 0; s < 4; ++s) {
    l += Lpart[s * (long)(HEADS * NQ) + hq];
    bf16x8 v = *(const bf16x8*)(Opart + (s * (long)(HEADS * NQ) + hq) * DH + d8 * 8);
#pragma unroll
    for (int j = 0; j < 8; ++j) acc[j] += (float)v[j];
  }
  const float inv = 1.f / l;
  f32x4 o0 = { acc[0] * inv, acc[1] * inv, acc[2] * inv, acc[3] * inv };
  f32x4 o1 = { acc[4] * inv, acc[5] * inv, acc[6] * inv, acc[7] * inv };
  float* op = Out + hq * DH + d8 * 8;
  *(f32x4*)(op)     = o0;
  *(f32x4*)(op + 4) = o1;
}

// ---------------------------------------------------------------------------
extern "C" void kernel_launch(void* const* d_in, const int* in_sizes, int n_in,
                              void* d_out, int out_size, void* d_ws, size_t ws_size,
                              hipStream_t stream)
{
  const float* Q = (const float*)d_in[0];
  const float* K = (const float*)d_in[1];
  const float* V = (const float*)d_in[2];
  const float* R = (const float*)d_in[3];
  float* Out = (float*)d_out;

  char* ws = (char*)d_ws;
  bf16_t* Qp = (bf16_t*)(ws);                          //  4 MiB: [16][2048][64]
  bf16_t* Kp = (bf16_t*)(ws + (size_t)(4  << 20));     //  8 MiB: [16][4096][64]
  bf16_t* Vt = (bf16_t*)(ws + (size_t)(12 << 20));     // 16 MiB: [16][128][4096]
  bf16_t* Opart = (bf16_t*)(ws + (size_t)(28 << 20));  // 32 MiB: [4][16][2048][128]
  float*  Lpart = (float*)(ws + (size_t)(60 << 20));   //  0.5 MiB: [4][16][2048]

  const size_t need4 = (size_t)(60 << 20) + 4ull * HEADS * NQ * sizeof(float);
  const int splits = (ws_size >= need4) ? 4 : 1;
  const int iters  = NKV / (64 * splits);

  prep_kernel<<<2560, 256, 0, stream>>>(Q, K, V, R, Qp, Kp, Vt);
  flash_kernel<<<splits * 256, 256, 0, stream>>>(Qp, Kp, Vt, Opart, Lpart, Out,
                                                 splits, iters);
  if (splits == 4)
    combine_kernel<<<2048, 256, 0, stream>>>(Opart, Lpart, Out);
}

// Round 10
// 190.175 us; speedup vs baseline: 1.0238x; 1.0238x over previous
//
#include <hip/hip_runtime.h>

#define HEADS 16
#define NQ    2048
#define NKV   4096
#define DH    128
#define PDIM  64

typedef __bf16 bf16_t;
typedef bf16_t bf16x8 __attribute__((ext_vector_type(8)));
typedef bf16_t bf16x4 __attribute__((ext_vector_type(4)));
typedef bf16_t bf16x2 __attribute__((ext_vector_type(2)));
typedef float  f32x4  __attribute__((ext_vector_type(4)));
typedef float  f32x16 __attribute__((ext_vector_type(16)));
typedef int    i32x4  __attribute__((ext_vector_type(4)));

typedef __attribute__((address_space(3))) unsigned int       lds_u32;
typedef __attribute__((address_space(1))) const unsigned int glb_u32;

__device__ __forceinline__ void dma16(const void* g, void* l) {
  __builtin_amdgcn_global_load_lds((glb_u32*)g, (lds_u32*)l, 16, 0, 0);
}

// ---------------------------------------------------------------------------
// prep (r6-proven: merged 3-launch pipeline):
//   blocks [0,512):      Q -> Qp (scaled by (1/8)*log2e)   [proj path]
//   blocks [512,1536):   K -> Kp                            [proj path]
//   blocks [1536,2560):  V -> Vt (bf16 transpose)           [vtrans path]
// ---------------------------------------------------------------------------
__global__ __launch_bounds__(256) void prep_kernel(
    const float* __restrict__ Q, const float* __restrict__ K,
    const float* __restrict__ V, const float* __restrict__ R,
    bf16_t* __restrict__ Qp, bf16_t* __restrict__ Kp, bf16_t* __restrict__ Vt)
{
  __shared__ char lds[32768];
  const int tid = threadIdx.x;
  const int bid = blockIdx.x;

  if (bid >= 1536) {
    // ---- V transpose path ----
    float* sF = (float*)lds;                   // 64 x 128 f32, granule-swizzled
    const int vb = bid - 1536;
    const float* tp = V + (long)vb * 64 * DH;
#pragma unroll
    for (int rep = 0; rep < 8; ++rep) {
      const int slot = tid + rep * 256;        // 2048 granules: 64 rows x 32
      const int j = slot >> 5, g = slot & 31;
      f32x4 v = *(const f32x4*)(tp + j * DH + g * 4);
      *(f32x4*)(&sF[j * 128 + ((g ^ ((j >> 3) & 7)) << 2)]) = v;
    }
    __syncthreads();

    const int h = vb >> 6, jt = vb & 63;
    bf16_t* op = Vt + (long)h * DH * NKV + jt * 64;
#pragma unroll
    for (int rep = 0; rep < 4; ++rep) {
      const int slot = tid + rep * 256;        // 1024 slots: 128 d x 8 j-groups
      const int d = slot >> 3, j8 = (slot & 7) * 8;
      const int key = slot & 7;                // == (j>>3)&7 for j in [j8,j8+8)
      const int gsw = (((d >> 2) ^ key) << 2) + (d & 3);
      bf16x8 w;
#pragma unroll
      for (int jj = 0; jj < 8; ++jj) w[jj] = (bf16_t)sF[(j8 + jj) * 128 + gsw];
      *(bf16x8*)(op + (long)d * NKV + j8) = w;
    }
    return;
  }

  // ---- projection path (Q or K) ----
  bf16_t* sR = (bf16_t*)lds;                   // [64][136] bf16 (17.4 KB)
  bf16_t* sYb = (bf16_t*)(lds + 64 * 136 * 2); // 4 x [16*72] bf16 (9.2 KB)

  const int isQ = (bid < 512);
  const float* src = isQ ? Q : K;
  const long row0  = isQ ? (long)bid * 64 : (long)(bid - 512) * 64;
  const float scale = isQ ? 0.18033688011112042f : 1.0f;   // (1/8)*log2(e)
  bf16_t* Y = isQ ? Qp : Kp;

  // R -> LDS transpose: sR[n][k] = R[k][n]; reads R linearly (coalesced).
#pragma unroll
  for (int rep = 0; rep < 32; ++rep) {
    const int idx = tid + rep * 256;           // 8192 elems, k = idx>>6, n low
    sR[(idx & 63) * 136 + (idx >> 6)] = (bf16_t)R[idx];
  }
  __syncthreads();

  const int wave = tid >> 6, lane = tid & 63;
  const int n16  = lane & 15, quad = lane >> 4;

  // B fragments: B[k][n], n = nt*16+n16, k = kk*32 + quad*8 + j
  bf16x8 bfr[4][4];
#pragma unroll
  for (int nt = 0; nt < 4; ++nt)
#pragma unroll
    for (int kk = 0; kk < 4; ++kk)
      bfr[nt][kk] = *(const bf16x8*)(sR + (nt * 16 + n16) * 136 + kk * 32 + quad * 8);

  // A fragments: row = wave*16 + n16, k = kk*32 + quad*8 + j, direct global
  const int arow = wave * 16 + n16;
  const float* xp = src + (row0 + arow) * DH;
  bf16x8 a[4];
#pragma unroll
  for (int kk = 0; kk < 4; ++kk) {
    const int k0 = kk * 32 + quad * 8;
    f32x4 x0 = *(const f32x4*)(xp + k0);
    f32x4 x1 = *(const f32x4*)(xp + k0 + 4);
    bf16x8 av;
#pragma unroll
    for (int j = 0; j < 4; ++j) { av[j] = (bf16_t)(x0[j] * scale); av[4 + j] = (bf16_t)(x1[j] * scale); }
    a[kk] = av;
  }

  bf16_t* sy = sYb + wave * (16 * 72);
#pragma unroll
  for (int nt = 0; nt < 4; ++nt) {
    f32x4 acc = {0.f, 0.f, 0.f, 0.f};
#pragma unroll
    for (int kk = 0; kk < 4; ++kk)
      acc = __builtin_amdgcn_mfma_f32_16x16x32_bf16(a[kk], bfr[nt][kk], acc, 0, 0, 0);
#pragma unroll
    for (int r = 0; r < 4; ++r)
      sy[(quad * 4 + r) * 72 + nt * 16 + n16] = (bf16_t)acc[r];
  }
  // coalesced store: lane -> (row = lane>>2, colgroup = lane&3)
  const long xrow = row0 + wave * 16;
  const int row = lane >> 2, cg = lane & 3;
  bf16x8 w0 = *(const bf16x8*)(&sy[row * 72 + cg * 16]);
  bf16x8 w1 = *(const bf16x8*)(&sy[row * 72 + cg * 16 + 8]);
  *(bf16x8*)(Y + (xrow + row) * PDIM + cg * 16)     = w0;
  *(bf16x8*)(Y + (xrow + row) * PDIM + cg * 16 + 8) = w1;
}

// ---------------------------------------------------------------------------
// flash v12 = v9 compute body (4 waves x 32 q, 64 acc regs, VGPR 64 —
// large regalloc headroom) + double-buffered dma16 pipeline with raw
// barriers (m201 pattern):
//   * STAGE(t+1) issued BEFORE compute(t); the 6 DMAs/wave target the
//     OTHER 24 KB buffer and stay in flight under ~2000 cyc of MFMA.
//   * one asm vmcnt(0) + s_barrier + sched_barrier(0) per iter, placed
//     AFTER compute — the wait is then nearly free (loads issued a full
//     compute-phase earlier).
//   * NO __syncthreads in the loop (its forced vmcnt(0)-before-barrier is
//     the serial drain that r8's accounting identified as the common ~40%
//     stall across v4/v9/v10).
// r1 tried this shape on the 128-acc 256-q body and spilled (WRITE 193MB);
// v9's 64-acc body has the headroom r1 lacked.
// Tripwires: FETCH ~14-19MB / WRITE ~33MB, VGPR <= ~110; else revert v9.
// LDS 48 KB -> 3 blocks/CU (12 waves/CU vs v9's 16).
// ---------------------------------------------------------------------------
__global__ __launch_bounds__(256, 3) void flash_kernel(
    const bf16_t* __restrict__ Qp, const bf16_t* __restrict__ Kp,
    const bf16_t* __restrict__ Vt, bf16_t* __restrict__ Opart,
    float* __restrict__ Lpart, float* __restrict__ Out,
    int splits, int iters)
{
  __shared__ char smem[49152];           // 2 x (8 KB K + 16 KB V)

  const int tid  = threadIdx.x;
  const int wave = tid >> 6, lane = tid & 63;
  const int l31  = lane & 31, h = lane >> 5;

  const int head = blockIdx.x & 15;      // XCD round-robin -> 2 heads/XCD
  const int qt   = (blockIdx.x >> 4) & 15;
  const int sp   = blockIdx.x >> 8;

  const int qbase = qt * 128 + wave * 32;   // each wave owns 32 q rows
  const int kv0   = sp * (64 * iters);

  // persistent Q B-frags: B[k=p][n=q], q = l31, p = k*16 + 8h + j
  bf16x8 qf[4];
#pragma unroll
  for (int k = 0; k < 4; ++k)
    qf[k] = *(const bf16x8*)(Qp + ((long)head * NQ + qbase + l31) * PDIM
                             + k * 16 + h * 8);

  f32x16 o[4] = {};             // O^T accum: [dsub], C layout (64 regs)
  float rsum = 0.f;             // per-lane partial row sum

  const bf16_t* kpH = Kp + (long)head * NKV * PDIM;
  const bf16_t* vtH = Vt + (long)head * DH * NKV;

  const int sw = ((lane & 7) ^ ((lane >> 3) & 7)) * 8;  // src-col swizzle (elems)
  const int r8 = lane >> 3;                             // row within 8-row group

  // 24 dma16 chunks/tile: 0..7 = K (8 KB), 8..23 = V (16 KB); 6 per wave.
#define STAGE(BASE, KVB)                                                      \
  {                                                                           \
    const int kb_ = (KVB);                                                    \
    char* b_ = (BASE);                                                        \
    if (wave == 0) {                                                          \
      _Pragma("unroll")                                                       \
      for (int i = 0; i < 6; ++i)                                             \
        dma16(kpH + (long)(kb_ + i * 8 + r8) * PDIM + sw, b_ + i * 1024);     \
    } else if (wave == 1) {                                                   \
      _Pragma("unroll")                                                       \
      for (int i = 6; i < 8; ++i)                                             \
        dma16(kpH + (long)(kb_ + i * 8 + r8) * PDIM + sw, b_ + i * 1024);     \
      _Pragma("unroll")                                                       \
      for (int i = 0; i < 4; ++i)                                             \
        dma16(vtH + (long)(i * 8 + r8) * NKV + kb_ + sw,                      \
              b_ + 8192 + i * 1024);                                          \
    } else if (wave == 2) {                                                   \
      _Pragma("unroll")                                                       \
      for (int i = 4; i < 10; ++i)                                            \
        dma16(vtH + (long)(i * 8 + r8) * NKV + kb_ + sw,                      \
              b_ + 8192 + i * 1024);                                          \
    } else {                                                                  \
      _Pragma("unroll")                                                       \
      for (int i = 10; i < 16; ++i)                                           \
        dma16(vtH + (long)(i * 8 + r8) * NKV + kb_ + sw,                      \
              b_ + 8192 + i * 1024);                                          \
    }                                                                         \
  }

  // prologue: stage tile 0, drain, publish
  STAGE(smem, kv0);
  asm volatile("s_waitcnt vmcnt(0)" ::: "memory");
  __builtin_amdgcn_s_barrier();
  __builtin_amdgcn_sched_barrier(0);

  for (int t = 0; t < iters; ++t) {
    char* cur = smem + ((t & 1) ? 24576 : 0);
    // issue-early: next tile's DMAs target the OTHER buffer and ride under
    // this tile's compute.
    if (t + 1 < iters)
      STAGE(smem + ((t & 1) ? 0 : 24576), kv0 + (t + 1) * 64);

    bf16_t* sK = (bf16_t*)cur;             // 64 rows x 64, swizzled chunks
    bf16_t* sV = (bf16_t*)(cur + 8192);    // 128 rows x 64, swizzled

#pragma unroll
    for (int s = 0; s < 2; ++s) {
      // QK: S^T tile [32 kv][32 q], kv row = s*32 + l31
      f32x16 sc = {};
      const int r = s * 32 + l31;
#pragma unroll
      for (int k = 0; k < 4; ++k) {
        const int c = 2 * k + h;
        const bf16x8 a = *(const bf16x8*)(sK + r * 64 + ((c ^ (r & 7)) * 8));
        sc = __builtin_amdgcn_mfma_f32_32x32x16_bf16(a, qf[k], sc, 0, 0, 0);
      }
      // exp2 (log2-domain, fixed max 0) + pack + per-lane rsum
      int pk[4][2];
#pragma unroll
      for (int rg = 0; rg < 4; ++rg) {
        const float p0 = __builtin_amdgcn_exp2f(sc[rg * 4 + 0]);
        const float p1 = __builtin_amdgcn_exp2f(sc[rg * 4 + 1]);
        const float p2 = __builtin_amdgcn_exp2f(sc[rg * 4 + 2]);
        const float p3 = __builtin_amdgcn_exp2f(sc[rg * 4 + 3]);
        rsum += (p0 + p1) + (p2 + p3);
        union { bf16x2 v; int i; } u0, u1;
        u0.v = bf16x2{(bf16_t)p0, (bf16_t)p1};
        u1.v = bf16x2{(bf16_t)p2, (bf16_t)p3};
        pk[rg][0] = u0.i; pk[rg][1] = u1.i;
      }
      // C-layout -> B-layout: j0-3 = half0's pk[2cl+h], j4-7 = half1's
      int bfr[2][4];
#pragma unroll
      for (int cl = 0; cl < 2; ++cl) {
        const int e00 = __shfl_xor(pk[2 * cl][0], 32);
        const int e01 = __shfl_xor(pk[2 * cl][1], 32);
        const int e10 = __shfl_xor(pk[2 * cl + 1][0], 32);
        const int e11 = __shfl_xor(pk[2 * cl + 1][1], 32);
        bfr[cl][0] = h ? e10 : pk[2 * cl][0];
        bfr[cl][1] = h ? e11 : pk[2 * cl][1];
        bfr[cl][2] = h ? pk[2 * cl + 1][0] : e00;
        bfr[cl][3] = h ? pk[2 * cl + 1][1] : e01;
      }
      // PV for this s: kv steps c = 2s + cl
#pragma unroll
      for (int dsub = 0; dsub < 4; ++dsub) {
        const int rr = dsub * 32 + l31;
#pragma unroll
        for (int cl = 0; cl < 2; ++cl) {
          const int c = 2 * (2 * s + cl) + h;
          const bf16x8 va = *(const bf16x8*)(sV + rr * 64 + ((c ^ (rr & 7)) * 8));
          union { i32x4 i; bf16x8 v; } pb;
          pb.i = i32x4{bfr[cl][0], bfr[cl][1], bfr[cl][2], bfr[cl][3]};
          o[dsub] = __builtin_amdgcn_mfma_f32_32x32x16_bf16(va, pb.v, o[dsub], 0, 0, 0);
        }
      }
    }

    // my 6 DMAs (issued a full compute-phase ago) drain cheaply; barrier
    // publishes them + guarantees nobody still reads the buffer the next
    // STAGE overwrites.
    asm volatile("s_waitcnt vmcnt(0)" ::: "memory");
    __builtin_amdgcn_s_barrier();
    __builtin_amdgcn_sched_barrier(0);
  }

  // epilogue: transpose O^T -> row-major via wave-private LDS, store coalesced
  __syncthreads();
  bf16_t* myT = (bf16_t*)(smem + wave * 8704);   // 32 rows x 272 B (136 elems)
  const float lsum = rsum + __shfl_xor(rsum, 32);
  const float scale = (splits > 1) ? 1.0f : (1.0f / lsum);
#pragma unroll
  for (int dsub = 0; dsub < 4; ++dsub)
#pragma unroll
    for (int rg = 0; rg < 4; ++rg) {
      bf16x4 w = { (bf16_t)(o[dsub][rg * 4 + 0] * scale),
                   (bf16_t)(o[dsub][rg * 4 + 1] * scale),
                   (bf16_t)(o[dsub][rg * 4 + 2] * scale),
                   (bf16_t)(o[dsub][rg * 4 + 3] * scale) };
      *(bf16x4*)(myT + l31 * 136 + dsub * 32 + rg * 8 + h * 4) = w;
    }
#pragma unroll
  for (int j = 0; j < 8; ++j) {
    const int ql = j * 4 + (lane >> 4);
    bf16x8 v = *(const bf16x8*)(myT + ql * 136 + (lane & 15) * 8);
    if (splits > 1) {
      *(bf16x8*)(Opart + (((long)sp * HEADS + head) * NQ + qbase + ql) * DH + (lane & 15) * 8) = v;
    } else {
      float* op = Out + ((long)head * NQ + qbase + ql) * DH + (lane & 15) * 8;
      f32x4 a = {(float)v[0], (float)v[1], (float)v[2], (float)v[3]};
      f32x4 b = {(float)v[4], (float)v[5], (float)v[6], (float)v[7]};
      *(f32x4*)op = a; *(f32x4*)(op + 4) = b;
    }
  }
  if (splits > 1 && h == 0)
    Lpart[((long)sp * HEADS + head) * NQ + qbase + l31] = lsum;
#undef STAGE
}

// ---------------------------------------------------------------------------
// combine: Out[hq][d] = (sum_s Opart[s][hq][d]) / (sum_s Lpart[s][hq])
// (round-0 form, fixed 4 splits)
// ---------------------------------------------------------------------------
__global__ __launch_bounds__(256) void combine_kernel(
    const bf16_t* __restrict__ Opart, const float* __restrict__ Lpart,
    float* __restrict__ Out)
{
  const long idx = (long)blockIdx.x * 256 + threadIdx.x;
  const int  d8  = (int)(idx & 15);
  const long hq  = idx >> 4;
  float l = 0.f;
  float acc[8];
#pragma unroll
  for (int j = 0; j < 8; ++j) acc[j] = 0.f;
#pragma unroll
  for (int s = 0; s < 4; ++s) {
    l += Lpart[s * (long)(HEADS * NQ) + hq];
    bf16x8 v = *(const bf16x8*)(Opart + (s * (long)(HEADS * NQ) + hq) * DH + d8 * 8);
#pragma unroll
    for (int j = 0; j < 8; ++j) acc[j] += (float)v[j];
  }
  const float inv = 1.f / l;
  f32x4 o0 = { acc[0] * inv, acc[1] * inv, acc[2] * inv, acc[3] * inv };
  f32x4 o1 = { acc[4] * inv, acc[5] * inv, acc[6] * inv, acc[7] * inv };
  float* op = Out + hq * DH + d8 * 8;
  *(f32x4*)(op)     = o0;
  *(f32x4*)(op + 4) = o1;
}

// ---------------------------------------------------------------------------
extern "C" void kernel_launch(void* const* d_in, const int* in_sizes, int n_in,
                              void* d_out, int out_size, void* d_ws, size_t ws_size,
                              hipStream_t stream)
{
  const float* Q = (const float*)d_in[0];
  const float* K = (const float*)d_in[1];
  const float* V = (const float*)d_in[2];
  const float* R = (const float*)d_in[3];
  float* Out = (float*)d_out;

  char* ws = (char*)d_ws;
  bf16_t* Qp = (bf16_t*)(ws);                          //  4 MiB: [16][2048][64]
  bf16_t* Kp = (bf16_t*)(ws + (size_t)(4  << 20));     //  8 MiB: [16][4096][64]
  bf16_t* Vt = (bf16_t*)(ws + (size_t)(12 << 20));     // 16 MiB: [16][128][4096]
  bf16_t* Opart = (bf16_t*)(ws + (size_t)(28 << 20));  // 32 MiB: [4][16][2048][128]
  float*  Lpart = (float*)(ws + (size_t)(60 << 20));   //  0.5 MiB: [4][16][2048]

  const size_t need4 = (size_t)(60 << 20) + 4ull * HEADS * NQ * sizeof(float);
  const int splits = (ws_size >= need4) ? 4 : 1;
  const int iters  = NKV / (64 * splits);

  prep_kernel<<<2560, 256, 0, stream>>>(Q, K, V, R, Qp, Kp, Vt);
  flash_kernel<<<splits * 256, 256, 0, stream>>>(Qp, Kp, Vt, Opart, Lpart, Out,
                                                 splits, iters);
  if (splits == 4)
    combine_kernel<<<2048, 256, 0, stream>>>(Opart, Lpart, Out);
}